// Round 5
// baseline (243.465 us; speedup 1.0000x reference)
//
#include <hip/hip_runtime.h>
#include <hip/hip_cooperative_groups.h>
#include <math.h>

#define TT 2048
#define HH 128
#define ROWS 8
#define SP 132           // LDS row stride (floats)
#define NBLK (TT / ROWS) // 256 blocks = 1 per CU

namespace cg = cooperative_groups;

struct Params {
    const float* emb; const int* start;
    const float* w_in; const float* b_in;
    const float* w_out; const float* b_out;
    const float* w_f; const float* b_f;
    const float* w_i; const float* b_i;
    const float* w_v; const float* b_v;
    const float* w_q; const float* b_q;
    const float* w_k; const float* b_k;
    const float* w_o; const float* b_o;
    const float* w_ff; const float* b_ff;
    float* out;
    float* k0; float* v0; float* aux0;
    float* k1; float* v1; float* aux1;
};

__device__ __forceinline__ float dot4(float4 a, float4 b) {
    return a.x * b.x + a.y * b.y + a.z * b.z + a.w * b.w;
}

// 128-dot: w = global row, x = LDS row. 8-load batches for VMEM pipelining.
__device__ __forceinline__ float gemv128(const float* __restrict__ w,
                                         const float* __restrict__ x) {
    float acc = 0.f;
    for (int cc = 0; cc < 128; cc += 32) {
        float4 w0 = *(const float4*)(w + cc);
        float4 w1 = *(const float4*)(w + cc + 4);
        float4 w2 = *(const float4*)(w + cc + 8);
        float4 w3 = *(const float4*)(w + cc + 12);
        float4 w4 = *(const float4*)(w + cc + 16);
        float4 w5 = *(const float4*)(w + cc + 20);
        float4 w6 = *(const float4*)(w + cc + 24);
        float4 w7 = *(const float4*)(w + cc + 28);
        float4 x0 = *(const float4*)(x + cc);
        float4 x1 = *(const float4*)(x + cc + 4);
        float4 x2 = *(const float4*)(x + cc + 8);
        float4 x3 = *(const float4*)(x + cc + 12);
        float4 x4 = *(const float4*)(x + cc + 16);
        float4 x5 = *(const float4*)(x + cc + 20);
        float4 x6 = *(const float4*)(x + cc + 24);
        float4 x7 = *(const float4*)(x + cc + 28);
        acc += dot4(x0, w0) + dot4(x1, w1) + dot4(x2, w2) + dot4(x3, w3);
        acc += dot4(x4, w4) + dot4(x5, w5) + dot4(x6, w6) + dot4(x7, w7);
    }
    return acc;
}

// 4-matrix fused projection + f/i gates. thread = (row=tid&7, h=tid>>3).
__device__ __forceinline__ void proj_phase(const Params& p, int layer, int t0,
        int row, int h, int wv, int lane, const float* __restrict__ xls,
        float* __restrict__ kb, float* __restrict__ vb, float* __restrict__ aux,
        float* __restrict__ qls, float* __restrict__ ols) {
    const int lo = layer * HH * HH;
    const float* wvp = p.w_v + lo + h * HH;
    const float* wqp = p.w_q + lo + h * HH;
    const float* wkp = p.w_k + lo + h * HH;
    const float* wop = p.w_o + lo + h * HH;
    const float* xr = xls + row * SP;
    float av = 0.f, aq = 0.f, ak = 0.f, ao = 0.f;
    for (int cc = 0; cc < HH; cc += 8) {
        float4 a0 = *(const float4*)(wvp + cc);
        float4 a1 = *(const float4*)(wvp + cc + 4);
        float4 b0 = *(const float4*)(wqp + cc);
        float4 b1 = *(const float4*)(wqp + cc + 4);
        float4 c0 = *(const float4*)(wkp + cc);
        float4 c1 = *(const float4*)(wkp + cc + 4);
        float4 d0 = *(const float4*)(wop + cc);
        float4 d1 = *(const float4*)(wop + cc + 4);
        float4 x0 = *(const float4*)(xr + cc);
        float4 x1 = *(const float4*)(xr + cc + 4);
        av += dot4(x0, a0) + dot4(x1, a1);
        aq += dot4(x0, b0) + dot4(x1, b1);
        ak += dot4(x0, c0) + dot4(x1, c1);
        ao += dot4(x0, d0) + dot4(x1, d1);
    }
    const float ksc = 0.088388347648318447f;  // 1/sqrt(128)
    int t = t0 + row;
    vb[t * HH + h] = av + p.b_v[layer * HH + h];
    kb[t * HH + h] = ak * ksc + p.b_k[layer * HH + h];
    qls[row * SP + h] = aq + p.b_q[layer * HH + h];
    ols[row * SP + h] = 1.f / (1.f + expf(-(ao + p.b_o[layer * HH + h])));
    // f/i gates: waves 0-7, wave wv owns row wv; lane covers dims {2l, 2l+1}.
    if (wv < 8) {
        const float* x = xls + wv * SP + 2 * lane;
        const float* wf = p.w_f + layer * HH;
        const float* wi = p.w_i + layer * HH;
        float pf = x[0] * wf[2 * lane] + x[1] * wf[2 * lane + 1];
        float pi = x[0] * wi[2 * lane] + x[1] * wi[2 * lane + 1];
#pragma unroll
        for (int off = 1; off <= 32; off <<= 1) {
            pf += __shfl_xor(pf, off, 64);
            pi += __shfl_xor(pi, off, 64);
        }
        if (lane == 0) {
            int tt = t0 + wv;
            int st = p.start[tt];
            float gg = st ? 0.f : 1.f / (1.f + expf(-(pf + p.b_f[layer])));
            float ie = expf(pi + p.b_i[layer]);
            *(float4*)(aux + tt * 4) = make_float4(gg, ie, st ? 1.f : 0.f, 0.f);
        }
    }
}

// mLSTM attention: wave wv (<8) owns row t0+wv; lane covers dims {2l,2l+1}.
// Backward walk within episode segment with one-step speculative prefetch.
__device__ __forceinline__ void attn_phase(int t0, int wv, int lane,
        const float* __restrict__ kb, const float* __restrict__ vb,
        const float* __restrict__ aux, const float* __restrict__ qls,
        const float* __restrict__ ols, float* __restrict__ hsb) {
    int t = t0 + wv;
    float2 q2 = *(const float2*)(qls + wv * SP + 2 * lane);
    float nx = 0.f, ny = 0.f, dsum = 0.f, decay = 1.f;
    int tp = t;
    float2 k2 = *(const float2*)(kb + tp * HH + 2 * lane);
    float2 v2 = *(const float2*)(vb + tp * HH + 2 * lane);
    float4 a4 = *(const float4*)(aux + tp * 4);  // {g, iexp, startflag, 0}
    while (true) {
        int tn = (tp > 0) ? tp - 1 : 0;
        float2 k2n = *(const float2*)(kb + tn * HH + 2 * lane);
        float2 v2n = *(const float2*)(vb + tn * HH + 2 * lane);
        float4 a4n = *(const float4*)(aux + tn * 4);
        float pp = k2.x * q2.x + k2.y * q2.y;
#pragma unroll
        for (int off = 1; off <= 32; off <<= 1) pp += __shfl_xor(pp, off, 64);
        float coeff = decay * a4.y * pp;
        nx += coeff * v2.x; ny += coeff * v2.y;
        dsum += coeff;
        if (tp == 0 || a4.z != 0.f) break;
        decay *= a4.x;
        tp = tn; k2 = k2n; v2 = v2n; a4 = a4n;
    }
    float inv = 1.f / fmaxf(fabsf(dsum), 1.f);
    float2 o2 = *(const float2*)(ols + wv * SP + 2 * lane);
    *(float2*)(hsb + wv * SP + 2 * lane) = make_float2(o2.x * nx * inv, o2.y * ny * inv);
}

// ff: z[row][h] = lrelu(dot(h_row, w[0:128]) + dot(e_row, w[128:256]) + b)
__device__ __forceinline__ void ff_phase(const float* __restrict__ wrow, float bff,
        int row, int h, const float* __restrict__ hsb, const float* __restrict__ esb,
        float* __restrict__ zsb) {
    const float* hr = hsb + row * SP;
    const float* er = esb + row * SP;
    float acc = 0.f;
    for (int cc = 0; cc < 128; cc += 8) {
        float4 wa0 = *(const float4*)(wrow + cc);
        float4 wa1 = *(const float4*)(wrow + cc + 4);
        float4 wb0 = *(const float4*)(wrow + 128 + cc);
        float4 wb1 = *(const float4*)(wrow + 128 + cc + 4);
        float4 xh0 = *(const float4*)(hr + cc);
        float4 xh1 = *(const float4*)(hr + cc + 4);
        float4 xe0 = *(const float4*)(er + cc);
        float4 xe1 = *(const float4*)(er + cc + 4);
        acc += dot4(xh0, wa0) + dot4(xh1, wa1);
        acc += dot4(xe0, wb0) + dot4(xe1, wb1);
    }
    acc += bff;
    acc = acc > 0.f ? acc : 0.01f * acc;
    zsb[row * SP + h] = acc;
}

__global__ __launch_bounds__(1024, 4) void kfused(Params p) {
    __shared__ float es[ROWS * SP];
    __shared__ float qls[ROWS * SP];
    __shared__ float ols[ROWS * SP];
    __shared__ float hs[ROWS * SP];
    __shared__ float zs[ROWS * SP];
    cg::grid_group grid = cg::this_grid();
    int tid = threadIdx.x;
    int t0 = blockIdx.x * ROWS;
    int row = tid & 7, h = tid >> 3;
    int wv = tid >> 6, lane = tid & 63;

    // ---------- Phase A: e = emb @ w_in.T + b_in (LDS only); layer-0 proj ----------
    {
        int r2 = tid >> 7, c2 = tid & 127;
        zs[r2 * SP + c2] = p.emb[(t0 + r2) * HH + c2];
    }
    __syncthreads();
    es[row * SP + h] = gemv128(p.w_in + h * HH, zs + row * SP) + p.b_in[h];
    __syncthreads();
    proj_phase(p, 0, t0, row, h, wv, lane, es, p.k0, p.v0, p.aux0, qls, ols);
    grid.sync();

    // ---------- Phase B: attn0 + ff0 + layer-1 proj ----------
    if (wv < 8) attn_phase(t0, wv, lane, p.k0, p.v0, p.aux0, qls, ols, hs);
    __syncthreads();
    ff_phase(p.w_ff + h * 256, p.b_ff[h], row, h, hs, es, zs);
    __syncthreads();
    proj_phase(p, 1, t0, row, h, wv, lane, zs, p.k1, p.v1, p.aux1, qls, ols);
    grid.sync();

    // ---------- Phase C: attn1 + ff1 + out ----------
    if (wv < 8) attn_phase(t0, wv, lane, p.k1, p.v1, p.aux1, qls, ols, hs);
    __syncthreads();
    ff_phase(p.w_ff + HH * 2 * HH + h * 256, p.b_ff[HH + h], row, h, hs, es, zs);
    __syncthreads();
    p.out[(t0 + row) * HH + h] = gemv128(p.w_out + h * HH, zs + row * SP) + p.b_out[h];
}

extern "C" void kernel_launch(void* const* d_in, const int* in_sizes, int n_in,
                              void* d_out, int out_size, void* d_ws, size_t ws_size,
                              hipStream_t stream) {
    Params prm;
    prm.emb   = (const float*)d_in[0];
    prm.start = (const int*)  d_in[1];
    prm.w_in  = (const float*)d_in[2];
    prm.b_in  = (const float*)d_in[3];
    prm.w_out = (const float*)d_in[4];
    prm.b_out = (const float*)d_in[5];
    prm.w_f   = (const float*)d_in[6];
    prm.b_f   = (const float*)d_in[7];
    prm.w_i   = (const float*)d_in[8];
    prm.b_i   = (const float*)d_in[9];
    prm.w_v   = (const float*)d_in[10];
    prm.b_v   = (const float*)d_in[11];
    prm.w_q   = (const float*)d_in[12];
    prm.b_q   = (const float*)d_in[13];
    prm.w_k   = (const float*)d_in[14];
    prm.b_k   = (const float*)d_in[15];
    prm.w_o   = (const float*)d_in[16];
    prm.b_o   = (const float*)d_in[17];
    prm.w_ff  = (const float*)d_in[18];
    prm.b_ff  = (const float*)d_in[19];
    prm.out   = (float*)d_out;

    float* ws = (float*)d_ws;
    prm.k0   = ws; ws += TT * HH;
    prm.v0   = ws; ws += TT * HH;
    prm.k1   = ws; ws += TT * HH;
    prm.v1   = ws; ws += TT * HH;
    prm.aux0 = ws; ws += TT * 4;
    prm.aux1 = ws; ws += TT * 4;

    void* args[] = { &prm };
    hipLaunchCooperativeKernel((void*)kfused, dim3(NBLK), dim3(1024), args, 0, stream);
}

// Round 7
// 224.094 us; speedup vs baseline: 1.0864x; 1.0864x over previous
//
#include <hip/hip_runtime.h>
#include <math.h>

#define TT 2048
#define HH 128
#define ROWS 8
#define SP 132   // activation LDS row stride
#define WS 132   // weight LDS row stride (conflict-free b128 at lane=h)
#define NB (TT / ROWS)
#define KS 0.088388347648318447f  // 1/sqrt(128)

struct P {
    const float* emb; const int* start;
    const float* w_in; const float* b_in;
    const float* w_out; const float* b_out;
    const float* w_f; const float* b_f;
    const float* w_i; const float* b_i;
    const float* w_v; const float* b_v;
    const float* w_q; const float* b_q;
    const float* w_k; const float* b_k;
    const float* w_o; const float* b_o;
    const float* w_ff; const float* b_ff;
    float* out;
    float* e;
    float* k0; float* v0; float* q0; float* o0; float* aux0;
    float* k1; float* v1; float* q1; float* o1; float* aux1;
};

__device__ __forceinline__ float dot4(float4 a, float4 b) {
    return a.x * b.x + a.y * b.y + a.z * b.z + a.w * b.w;
}

// Load a 128x128 fp32 slab (row stride ld, starting col cb) into 8 float4 regs.
// Coalesced: f = j*512 + tid indexes float4s row-major.
__device__ __forceinline__ void stage_g2r(const float* __restrict__ w, int ld, int cb,
                                          float4* st) {
    int tid = threadIdx.x;
#pragma unroll
    for (int j = 0; j < 8; j++) {
        int f = j * 512 + tid;
        int row = f >> 5;
        int col = (f & 31) << 2;
        st[j] = *(const float4*)(w + row * ld + cb + col);
    }
}
__device__ __forceinline__ void stage_r2l(float* __restrict__ b, const float4* st) {
    int tid = threadIdx.x;
#pragma unroll
    for (int j = 0; j < 8; j++) {
        int f = j * 512 + tid;
        int row = f >> 5;
        int col = (f & 31) << 2;
        *(float4*)(b + row * WS + col) = st[j];
    }
}

// GEMV for 2 rows from LDS weights (row h) and LDS activations.
__device__ __forceinline__ void gemv2(const float* __restrict__ wb, int h,
        const float* __restrict__ x0, const float* __restrict__ x1,
        float* a0, float* a1) {
    const float* wr = wb + h * WS;
    float s0 = 0.f, s1 = 0.f, t0 = 0.f, t1 = 0.f;
#pragma unroll
    for (int c = 0; c < 128; c += 8) {
        float4 w0 = *(const float4*)(wr + c);
        float4 w1 = *(const float4*)(wr + c + 4);
        float4 xa0 = *(const float4*)(x0 + c);
        float4 xa1 = *(const float4*)(x0 + c + 4);
        float4 xb0 = *(const float4*)(x1 + c);
        float4 xb1 = *(const float4*)(x1 + c + 4);
        s0 += dot4(xa0, w0); t0 += dot4(xa1, w1);
        s1 += dot4(xb0, w0); t1 += dot4(xb1, w1);
    }
    *a0 = s0 + t0;
    *a1 = s1 + t1;
}

// f/i gates: wave wv owns row wv (8 waves); writes aux[t] = {g, exp(i), startflag, 0}
__device__ __forceinline__ void gates(int t0, const float* __restrict__ xls,
        const float* __restrict__ wf, float bf, const float* __restrict__ wi, float bi,
        const int* __restrict__ start, float* __restrict__ aux) {
    int tid = threadIdx.x;
    int wv = tid >> 6, lane = tid & 63;
    const float* x = xls + wv * SP + 2 * lane;
    float pf = x[0] * wf[2 * lane] + x[1] * wf[2 * lane + 1];
    float pi = x[0] * wi[2 * lane] + x[1] * wi[2 * lane + 1];
#pragma unroll
    for (int off = 1; off <= 32; off <<= 1) {
        pf += __shfl_xor(pf, off, 64);
        pi += __shfl_xor(pi, off, 64);
    }
    if (lane == 0) {
        int t = t0 + wv;
        int st = start[t];
        float gg = st ? 0.f : 1.f / (1.f + expf(-(pf + bf)));
        *(float4*)(aux + t * 4) = make_float4(gg, expf(pi + bi), st ? 1.f : 0.f, 0.f);
    }
}

// mLSTM attention: wave wv owns row t0+wv; backward walk within episode segment.
__device__ __forceinline__ void attn_phase(int t0,
        const float* __restrict__ kb, const float* __restrict__ vb,
        const float* __restrict__ qb, const float* __restrict__ ob,
        const float* __restrict__ aux, float* __restrict__ hsb) {
    int tid = threadIdx.x;
    int wv = tid >> 6, lane = tid & 63;
    int t = t0 + wv;
    float2 q2 = *(const float2*)(qb + t * HH + 2 * lane);
    float nx = 0.f, ny = 0.f, dsum = 0.f, decay = 1.f;
    int tp = t;
    float2 k2 = *(const float2*)(kb + tp * HH + 2 * lane);
    float2 v2 = *(const float2*)(vb + tp * HH + 2 * lane);
    float4 a4 = *(const float4*)(aux + tp * 4);  // {g, iexp, startflag, 0}
    while (true) {
        int tn = (tp > 0) ? tp - 1 : 0;
        float2 k2n = *(const float2*)(kb + tn * HH + 2 * lane);
        float2 v2n = *(const float2*)(vb + tn * HH + 2 * lane);
        float4 a4n = *(const float4*)(aux + tn * 4);
        float pp = k2.x * q2.x + k2.y * q2.y;
#pragma unroll
        for (int off = 1; off <= 32; off <<= 1) pp += __shfl_xor(pp, off, 64);
        float coeff = decay * a4.y * pp;
        nx += coeff * v2.x; ny += coeff * v2.y;
        dsum += coeff;
        if (tp == 0 || a4.z != 0.f) break;
        decay *= a4.x;
        tp = tn; k2 = k2n; v2 = v2n; a4 = a4n;
    }
    float inv = 1.f / fmaxf(fabsf(dsum), 1.f);
    float2 o2 = *(const float2*)(ob + t * HH + 2 * lane);
    *(float2*)(hsb + wv * SP + 2 * lane) = make_float2(o2.x * nx * inv, o2.y * ny * inv);
}

// Stage 8 activation rows global->LDS (threads 0..255).
__device__ __forceinline__ void stage_rows(const float* __restrict__ src, int t0,
                                           float* __restrict__ dst) {
    int tid = threadIdx.x;
    if (tid < 256) {
        int row = tid >> 5, col = (tid & 31) << 2;
        *(float4*)(dst + row * SP + col) = *(const float4*)(src + (t0 + row) * HH + col);
    }
}

// ---------------- K1: e = emb @ w_in.T; layer-0 proj (v,q,k,o,f,i) ----------------
__global__ __launch_bounds__(512, 2) void k1(P p) {
    __shared__ float buf[2][HH * WS];
    __shared__ float xs[ROWS * SP];
    __shared__ float es[ROWS * SP];
    int tid = threadIdx.x;
    int t0 = blockIdx.x * ROWS;
    int h = tid & 127, s = tid >> 7;
    int r0 = 2 * s, r1 = 2 * s + 1;
    stage_rows(p.emb, t0, xs);
    float4 st[8];
    stage_g2r(p.w_in, 128, 0, st);
    stage_r2l(buf[0], st);
    __syncthreads();
    // e from buf0; stage w_v
    stage_g2r(p.w_v, 128, 0, st);
    float a0, a1;
    gemv2(buf[0], h, xs + r0 * SP, xs + r1 * SP, &a0, &a1);
    float bh = p.b_in[h];
    a0 += bh; a1 += bh;
    es[r0 * SP + h] = a0; es[r1 * SP + h] = a1;
    p.e[(t0 + r0) * HH + h] = a0; p.e[(t0 + r1) * HH + h] = a1;
    stage_r2l(buf[1], st);
    __syncthreads();
    gates(t0, es, p.w_f, p.b_f[0], p.w_i, p.b_i[0], p.start, p.aux0);
    // v from buf1; stage w_q
    stage_g2r(p.w_q, 128, 0, st);
    gemv2(buf[1], h, es + r0 * SP, es + r1 * SP, &a0, &a1);
    bh = p.b_v[h];
    p.v0[(t0 + r0) * HH + h] = a0 + bh; p.v0[(t0 + r1) * HH + h] = a1 + bh;
    stage_r2l(buf[0], st);
    __syncthreads();
    // q from buf0; stage w_k
    stage_g2r(p.w_k, 128, 0, st);
    gemv2(buf[0], h, es + r0 * SP, es + r1 * SP, &a0, &a1);
    bh = p.b_q[h];
    p.q0[(t0 + r0) * HH + h] = a0 + bh; p.q0[(t0 + r1) * HH + h] = a1 + bh;
    stage_r2l(buf[1], st);
    __syncthreads();
    // k from buf1; stage w_o
    stage_g2r(p.w_o, 128, 0, st);
    gemv2(buf[1], h, es + r0 * SP, es + r1 * SP, &a0, &a1);
    bh = p.b_k[h];
    p.k0[(t0 + r0) * HH + h] = a0 * KS + bh; p.k0[(t0 + r1) * HH + h] = a1 * KS + bh;
    stage_r2l(buf[0], st);
    __syncthreads();
    // o from buf0
    gemv2(buf[0], h, es + r0 * SP, es + r1 * SP, &a0, &a1);
    bh = p.b_o[h];
    p.o0[(t0 + r0) * HH + h] = 1.f / (1.f + expf(-(a0 + bh)));
    p.o0[(t0 + r1) * HH + h] = 1.f / (1.f + expf(-(a1 + bh)));
}

// ---------------- K2: attn0 + ff0 + layer-1 proj ----------------
__global__ __launch_bounds__(512, 2) void k2(P p) {
    __shared__ float buf[2][HH * WS];
    __shared__ float es[ROWS * SP];
    __shared__ float hs[ROWS * SP];
    __shared__ float zs[ROWS * SP];
    int tid = threadIdx.x;
    int t0 = blockIdx.x * ROWS;
    int h = tid & 127, s = tid >> 7;
    int r0 = 2 * s, r1 = 2 * s + 1;
    stage_rows(p.e, t0, es);
    float4 st[8];
    stage_g2r(p.w_ff, 256, 0, st);                       // ffA (h-half)
    attn_phase(t0, p.k0, p.v0, p.q0, p.o0, p.aux0, hs);
    stage_r2l(buf[0], st);
    __syncthreads();
    // ffA from buf0 (x = hs); stage ffB
    stage_g2r(p.w_ff, 256, 128, st);
    float fa0, fa1;
    gemv2(buf[0], h, hs + r0 * SP, hs + r1 * SP, &fa0, &fa1);
    stage_r2l(buf[1], st);
    __syncthreads();
    // ffB from buf1 (x = es); stage w_v1; z = lrelu
    stage_g2r(p.w_v + HH * HH, 128, 0, st);
    float fb0, fb1;
    gemv2(buf[1], h, es + r0 * SP, es + r1 * SP, &fb0, &fb1);
    float bh = p.b_ff[h];
    float z0 = fa0 + fb0 + bh, z1 = fa1 + fb1 + bh;
    z0 = z0 > 0.f ? z0 : 0.01f * z0;
    z1 = z1 > 0.f ? z1 : 0.01f * z1;
    zs[r0 * SP + h] = z0; zs[r1 * SP + h] = z1;
    stage_r2l(buf[0], st);
    __syncthreads();
    gates(t0, zs, p.w_f + HH, p.b_f[1], p.w_i + HH, p.b_i[1], p.start, p.aux1);
    // v1 from buf0; stage w_q1
    stage_g2r(p.w_q + HH * HH, 128, 0, st);
    float a0, a1;
    gemv2(buf[0], h, zs + r0 * SP, zs + r1 * SP, &a0, &a1);
    bh = p.b_v[HH + h];
    p.v1[(t0 + r0) * HH + h] = a0 + bh; p.v1[(t0 + r1) * HH + h] = a1 + bh;
    stage_r2l(buf[1], st);
    __syncthreads();
    // q1 from buf1; stage w_k1
    stage_g2r(p.w_k + HH * HH, 128, 0, st);
    gemv2(buf[1], h, zs + r0 * SP, zs + r1 * SP, &a0, &a1);
    bh = p.b_q[HH + h];
    p.q1[(t0 + r0) * HH + h] = a0 + bh; p.q1[(t0 + r1) * HH + h] = a1 + bh;
    stage_r2l(buf[0], st);
    __syncthreads();
    // k1 from buf0; stage w_o1
    stage_g2r(p.w_o + HH * HH, 128, 0, st);
    gemv2(buf[0], h, zs + r0 * SP, zs + r1 * SP, &a0, &a1);
    bh = p.b_k[HH + h];
    p.k1[(t0 + r0) * HH + h] = a0 * KS + bh; p.k1[(t0 + r1) * HH + h] = a1 * KS + bh;
    stage_r2l(buf[1], st);
    __syncthreads();
    // o1 from buf1
    gemv2(buf[1], h, zs + r0 * SP, zs + r1 * SP, &a0, &a1);
    bh = p.b_o[HH + h];
    p.o1[(t0 + r0) * HH + h] = 1.f / (1.f + expf(-(a0 + bh)));
    p.o1[(t0 + r1) * HH + h] = 1.f / (1.f + expf(-(a1 + bh)));
}

// ---------------- K3: attn1 + ff1 + final dense ----------------
__global__ __launch_bounds__(512, 2) void k3(P p) {
    __shared__ float buf[2][HH * WS];
    __shared__ float es[ROWS * SP];
    __shared__ float hs[ROWS * SP];
    __shared__ float zs[ROWS * SP];
    int tid = threadIdx.x;
    int t0 = blockIdx.x * ROWS;
    int h = tid & 127, s = tid >> 7;
    int r0 = 2 * s, r1 = 2 * s + 1;
    stage_rows(p.e, t0, es);
    const float* wff1 = p.w_ff + HH * 2 * HH;
    float4 st[8];
    stage_g2r(wff1, 256, 0, st);
    attn_phase(t0, p.k1, p.v1, p.q1, p.o1, p.aux1, hs);
    stage_r2l(buf[0], st);
    __syncthreads();
    stage_g2r(wff1, 256, 128, st);
    float fa0, fa1;
    gemv2(buf[0], h, hs + r0 * SP, hs + r1 * SP, &fa0, &fa1);
    stage_r2l(buf[1], st);
    __syncthreads();
    stage_g2r(p.w_out, 128, 0, st);
    float fb0, fb1;
    gemv2(buf[1], h, es + r0 * SP, es + r1 * SP, &fb0, &fb1);
    float bh = p.b_ff[HH + h];
    float z0 = fa0 + fb0 + bh, z1 = fa1 + fb1 + bh;
    z0 = z0 > 0.f ? z0 : 0.01f * z0;
    z1 = z1 > 0.f ? z1 : 0.01f * z1;
    zs[r0 * SP + h] = z0; zs[r1 * SP + h] = z1;
    stage_r2l(buf[0], st);
    __syncthreads();
    float a0, a1;
    gemv2(buf[0], h, zs + r0 * SP, zs + r1 * SP, &a0, &a1);
    bh = p.b_out[h];
    p.out[(t0 + r0) * HH + h] = a0 + bh;
    p.out[(t0 + r1) * HH + h] = a1 + bh;
}

extern "C" void kernel_launch(void* const* d_in, const int* in_sizes, int n_in,
                              void* d_out, int out_size, void* d_ws, size_t ws_size,
                              hipStream_t stream) {
    P p;
    p.emb   = (const float*)d_in[0];
    p.start = (const int*)  d_in[1];
    p.w_in  = (const float*)d_in[2];
    p.b_in  = (const float*)d_in[3];
    p.w_out = (const float*)d_in[4];
    p.b_out = (const float*)d_in[5];
    p.w_f   = (const float*)d_in[6];
    p.b_f   = (const float*)d_in[7];
    p.w_i   = (const float*)d_in[8];
    p.b_i   = (const float*)d_in[9];
    p.w_v   = (const float*)d_in[10];
    p.b_v   = (const float*)d_in[11];
    p.w_q   = (const float*)d_in[12];
    p.b_q   = (const float*)d_in[13];
    p.w_k   = (const float*)d_in[14];
    p.b_k   = (const float*)d_in[15];
    p.w_o   = (const float*)d_in[16];
    p.b_o   = (const float*)d_in[17];
    p.w_ff  = (const float*)d_in[18];
    p.b_ff  = (const float*)d_in[19];
    p.out   = (float*)d_out;

    float* ws = (float*)d_ws;
    p.e    = ws; ws += TT * HH;
    p.k0   = ws; ws += TT * HH;
    p.v0   = ws; ws += TT * HH;
    p.q0   = ws; ws += TT * HH;
    p.o0   = ws; ws += TT * HH;
    p.k1   = ws; ws += TT * HH;
    p.v1   = ws; ws += TT * HH;
    p.q1   = ws; ws += TT * HH;
    p.o1   = ws; ws += TT * HH;
    p.aux0 = ws; ws += TT * 4;
    p.aux1 = ws; ws += TT * 4;

    k1<<<dim3(NB), dim3(512), 0, stream>>>(p);
    k2<<<dim3(NB), dim3(512), 0, stream>>>(p);
    k3<<<dim3(NB), dim3(512), 0, stream>>>(p);
}

// Round 8
// 208.552 us; speedup vs baseline: 1.1674x; 1.0745x over previous
//
#include <hip/hip_runtime.h>
#include <math.h>

#define TT 2048
#define HH 128
#define ROWS 4
#define SP 132   // activation LDS row stride (pad)
#define NB (TT / ROWS)  // 512 blocks = 2 per CU
#define KS 0.088388347648318447f  // 1/sqrt(128)

struct P {
    const float* emb; const int* start;
    const float* w_in; const float* b_in;
    const float* w_out; const float* b_out;
    const float* w_f; const float* b_f;
    const float* w_i; const float* b_i;
    const float* w_v; const float* b_v;
    const float* w_q; const float* b_q;
    const float* w_k; const float* b_k;
    const float* w_o; const float* b_o;
    const float* w_ff; const float* b_ff;
    float* out;
    float* e;
    float* k0; float* v0; float* q0; float* o0; float* aux0;
    float* k1; float* v1; float* q1; float* o1; float* aux1;
};

__device__ __forceinline__ float dot4(float4 a, float4 b) {
    return a.x * b.x + a.y * b.y + a.z * b.z + a.w * b.w;
}

// Load 64 cols of weight row h (row stride ld), col offset q*64, into 16 float4 regs.
__device__ __forceinline__ void loadW(const float* __restrict__ wm, int ld, int h, int q,
                                      float4* r) {
    const float* base = wm + h * ld + q * 64;
#pragma unroll
    for (int j = 0; j < 16; j++) r[j] = *(const float4*)(base + 4 * j);
}

// acc[r] += dot(w_regs, x[r][q*64 : q*64+64])  -- x reads are LDS broadcasts
__device__ __forceinline__ void gemvRows(const float4* wr, const float* __restrict__ xls,
                                         int q, float* acc) {
#pragma unroll
    for (int r = 0; r < ROWS; r++) {
        const float* x = xls + r * SP + q * 64;
        float s = 0.f;
#pragma unroll
        for (int j = 0; j < 16; j++) s += dot4(*(const float4*)(x + 4 * j), wr[j]);
        acc[r] += s;
    }
}

// two matrices sharing the same x stream (halves the LDS broadcasts)
__device__ __forceinline__ void gemvPair(const float4* wa, const float4* wb,
                                         const float* __restrict__ xls, int q,
                                         float* aA, float* aB) {
#pragma unroll
    for (int r = 0; r < ROWS; r++) {
        const float* x = xls + r * SP + q * 64;
        float sa = 0.f, sb = 0.f;
#pragma unroll
        for (int j = 0; j < 16; j++) {
            float4 x4 = *(const float4*)(x + 4 * j);
            sa += dot4(x4, wa[j]);
            sb += dot4(x4, wb[j]);
        }
        aA[r] += sa; aB[r] += sb;
    }
}

// f/i gates: wave wv owns row wv (4 waves); writes aux[t] = {g, exp(i), startflag, 0}
__device__ __forceinline__ void gates(int t0, const float* __restrict__ xls,
        const float* __restrict__ wf, float bf, const float* __restrict__ wi, float bi,
        const int* __restrict__ start, float* __restrict__ aux) {
    int tid = threadIdx.x;
    int wv = tid >> 6, lane = tid & 63;
    const float* x = xls + wv * SP + 2 * lane;
    float pf = x[0] * wf[2 * lane] + x[1] * wf[2 * lane + 1];
    float pi = x[0] * wi[2 * lane] + x[1] * wi[2 * lane + 1];
#pragma unroll
    for (int off = 1; off <= 32; off <<= 1) {
        pf += __shfl_xor(pf, off, 64);
        pi += __shfl_xor(pi, off, 64);
    }
    if (lane == 0) {
        int t = t0 + wv;
        int st = start[t];
        float gg = st ? 0.f : 1.f / (1.f + expf(-(pf + bf)));
        *(float4*)(aux + t * 4) = make_float4(gg, expf(pi + bi), st ? 1.f : 0.f, 0.f);
    }
}

// mLSTM attention: wave wv owns row t0+wv; backward walk within episode segment.
__device__ __forceinline__ void attn_phase(int t0,
        const float* __restrict__ kb, const float* __restrict__ vb,
        const float* __restrict__ qb, const float* __restrict__ ob,
        const float* __restrict__ aux, float* __restrict__ hsb) {
    int tid = threadIdx.x;
    int wv = tid >> 6, lane = tid & 63;
    int t = t0 + wv;
    float2 q2 = *(const float2*)(qb + t * HH + 2 * lane);
    float nx = 0.f, ny = 0.f, dsum = 0.f, decay = 1.f;
    int tp = t;
    float2 k2 = *(const float2*)(kb + tp * HH + 2 * lane);
    float2 v2 = *(const float2*)(vb + tp * HH + 2 * lane);
    float4 a4 = *(const float4*)(aux + tp * 4);  // {g, iexp, startflag, 0}
    while (true) {
        int tn = (tp > 0) ? tp - 1 : 0;
        float2 k2n = *(const float2*)(kb + tn * HH + 2 * lane);
        float2 v2n = *(const float2*)(vb + tn * HH + 2 * lane);
        float4 a4n = *(const float4*)(aux + tn * 4);
        float pp = k2.x * q2.x + k2.y * q2.y;
#pragma unroll
        for (int off = 1; off <= 32; off <<= 1) pp += __shfl_xor(pp, off, 64);
        float coeff = decay * a4.y * pp;
        nx += coeff * v2.x; ny += coeff * v2.y;
        dsum += coeff;
        if (tp == 0 || a4.z != 0.f) break;
        decay *= a4.x;
        tp = tn; k2 = k2n; v2 = v2n; a4 = a4n;
    }
    float inv = 1.f / fmaxf(fabsf(dsum), 1.f);
    float2 o2 = *(const float2*)(ob + t * HH + 2 * lane);
    *(float2*)(hsb + wv * SP + 2 * lane) = make_float2(o2.x * nx * inv, o2.y * ny * inv);
}

// stage 4 activation rows global->LDS (threads 0..127)
__device__ __forceinline__ void stage_rows(const float* __restrict__ src, int t0,
                                           float* __restrict__ dst) {
    int tid = threadIdx.x;
    if (tid < 128) {
        int r = tid >> 5, c = (tid & 31) << 2;
        *(float4*)(dst + r * SP + c) = *(const float4*)(src + (t0 + r) * HH + c);
    }
}

// ---------------- K1: e = emb @ w_in.T + b; layer-0 proj ----------------
__global__ __launch_bounds__(256, 2) void k1(P p) {
    __shared__ float xs[ROWS * SP];
    __shared__ float es[ROWS * SP];
    int tid = threadIdx.x;
    int t0 = blockIdx.x * ROWS;
    int lane = tid & 63, w = tid >> 6;
    int h = w * 32 + (lane & 31), q = lane >> 5;
    stage_rows(p.emb, t0, xs);
    float4 wa[16], wb[16];
    loadW(p.w_in, 128, h, q, wa);
    __syncthreads();
    float acc[4] = {0.f, 0.f, 0.f, 0.f};
    gemvRows(wa, xs, q, acc);
    float be = p.b_in[h];
    loadW(p.w_v, 128, h, q, wa);
    loadW(p.w_q, 128, h, q, wb);
#pragma unroll
    for (int r = 0; r < 4; r++) acc[r] += __shfl_xor(acc[r], 32, 64);
    if (lane < 32) {
#pragma unroll
        for (int r = 0; r < 4; r++) {
            float v = acc[r] + be;
            es[r * SP + h] = v;
            p.e[(t0 + r) * HH + h] = v;
        }
    }
    __syncthreads();
    gates(t0, es, p.w_f, p.b_f[0], p.w_i, p.b_i[0], p.start, p.aux0);
    float aA[4] = {0.f, 0.f, 0.f, 0.f}, aB[4] = {0.f, 0.f, 0.f, 0.f};
    gemvPair(wa, wb, es, q, aA, aB);
    float bv = p.b_v[h], bq = p.b_q[h];
#pragma unroll
    for (int r = 0; r < 4; r++) {
        aA[r] += __shfl_xor(aA[r], 32, 64);
        aB[r] += __shfl_xor(aB[r], 32, 64);
    }
    if (lane < 32) {
#pragma unroll
        for (int r = 0; r < 4; r++) {
            p.v0[(t0 + r) * HH + h] = aA[r] + bv;
            p.q0[(t0 + r) * HH + h] = aB[r] + bq;
        }
    }
    loadW(p.w_k, 128, h, q, wa);
    loadW(p.w_o, 128, h, q, wb);
    float cA[4] = {0.f, 0.f, 0.f, 0.f}, cB[4] = {0.f, 0.f, 0.f, 0.f};
    gemvPair(wa, wb, es, q, cA, cB);
    float bk = p.b_k[h], bo = p.b_o[h];
#pragma unroll
    for (int r = 0; r < 4; r++) {
        cA[r] += __shfl_xor(cA[r], 32, 64);
        cB[r] += __shfl_xor(cB[r], 32, 64);
    }
    if (lane < 32) {
#pragma unroll
        for (int r = 0; r < 4; r++) {
            p.k0[(t0 + r) * HH + h] = cA[r] * KS + bk;
            p.o0[(t0 + r) * HH + h] = 1.f / (1.f + expf(-(cB[r] + bo)));
        }
    }
}

// ---------------- K2: attn0 + ff0 + layer-1 proj ----------------
__global__ __launch_bounds__(256, 2) void k2(P p) {
    __shared__ float es[ROWS * SP];
    __shared__ float hs[ROWS * SP];
    __shared__ float zs[ROWS * SP];
    int tid = threadIdx.x;
    int t0 = blockIdx.x * ROWS;
    int lane = tid & 63, w = tid >> 6;
    int h = w * 32 + (lane & 31), q = lane >> 5;
    stage_rows(p.e, t0, es);
    float4 wa[16], wb[16];
    loadW(p.w_ff, 256, h, q, wa);        // ff cols [0,128): multiplies h-part
    loadW(p.w_ff + 128, 256, h, q, wb);  // ff cols [128,256): multiplies e-part
    attn_phase(t0, p.k0, p.v0, p.q0, p.o0, p.aux0, hs);
    __syncthreads();
    float fA[4] = {0.f, 0.f, 0.f, 0.f}, fB[4] = {0.f, 0.f, 0.f, 0.f};
    gemvRows(wa, hs, q, fA);
    gemvRows(wb, es, q, fB);
    loadW(p.w_v + HH * HH, 128, h, q, wa);
    loadW(p.w_q + HH * HH, 128, h, q, wb);
    float bff = p.b_ff[h];
#pragma unroll
    for (int r = 0; r < 4; r++) {
        float z = fA[r] + fB[r];
        z += __shfl_xor(z, 32, 64);
        z += bff;
        z = z > 0.f ? z : 0.01f * z;
        fA[r] = z;
    }
    if (lane < 32) {
#pragma unroll
        for (int r = 0; r < 4; r++) zs[r * SP + h] = fA[r];
    }
    __syncthreads();
    gates(t0, zs, p.w_f + HH, p.b_f[1], p.w_i + HH, p.b_i[1], p.start, p.aux1);
    float aA[4] = {0.f, 0.f, 0.f, 0.f}, aB[4] = {0.f, 0.f, 0.f, 0.f};
    gemvPair(wa, wb, zs, q, aA, aB);
    float bv = p.b_v[HH + h], bq = p.b_q[HH + h];
#pragma unroll
    for (int r = 0; r < 4; r++) {
        aA[r] += __shfl_xor(aA[r], 32, 64);
        aB[r] += __shfl_xor(aB[r], 32, 64);
    }
    if (lane < 32) {
#pragma unroll
        for (int r = 0; r < 4; r++) {
            p.v1[(t0 + r) * HH + h] = aA[r] + bv;
            p.q1[(t0 + r) * HH + h] = aB[r] + bq;
        }
    }
    loadW(p.w_k + HH * HH, 128, h, q, wa);
    loadW(p.w_o + HH * HH, 128, h, q, wb);
    float cA[4] = {0.f, 0.f, 0.f, 0.f}, cB[4] = {0.f, 0.f, 0.f, 0.f};
    gemvPair(wa, wb, zs, q, cA, cB);
    float bk = p.b_k[HH + h], bo = p.b_o[HH + h];
#pragma unroll
    for (int r = 0; r < 4; r++) {
        cA[r] += __shfl_xor(cA[r], 32, 64);
        cB[r] += __shfl_xor(cB[r], 32, 64);
    }
    if (lane < 32) {
#pragma unroll
        for (int r = 0; r < 4; r++) {
            p.k1[(t0 + r) * HH + h] = cA[r] * KS + bk;
            p.o1[(t0 + r) * HH + h] = 1.f / (1.f + expf(-(cB[r] + bo)));
        }
    }
}

// ---------------- K3: attn1 + ff1 + final dense ----------------
__global__ __launch_bounds__(256, 2) void k3(P p) {
    __shared__ float es[ROWS * SP];
    __shared__ float hs[ROWS * SP];
    __shared__ float zs[ROWS * SP];
    int tid = threadIdx.x;
    int t0 = blockIdx.x * ROWS;
    int lane = tid & 63, w = tid >> 6;
    int h = w * 32 + (lane & 31), q = lane >> 5;
    stage_rows(p.e, t0, es);
    const float* wff1 = p.w_ff + HH * 2 * HH;
    float4 wa[16], wb[16];
    loadW(wff1, 256, h, q, wa);
    loadW(wff1 + 128, 256, h, q, wb);
    attn_phase(t0, p.k1, p.v1, p.q1, p.o1, p.aux1, hs);
    __syncthreads();
    float fA[4] = {0.f, 0.f, 0.f, 0.f}, fB[4] = {0.f, 0.f, 0.f, 0.f};
    gemvRows(wa, hs, q, fA);
    gemvRows(wb, es, q, fB);
    loadW(p.w_out, 128, h, q, wa);
    float bff = p.b_ff[HH + h];
#pragma unroll
    for (int r = 0; r < 4; r++) {
        float z = fA[r] + fB[r];
        z += __shfl_xor(z, 32, 64);
        z += bff;
        z = z > 0.f ? z : 0.01f * z;
        fA[r] = z;
    }
    if (lane < 32) {
#pragma unroll
        for (int r = 0; r < 4; r++) zs[r * SP + h] = fA[r];
    }
    __syncthreads();
    float acc[4] = {0.f, 0.f, 0.f, 0.f};
    gemvRows(wa, zs, q, acc);
    float bo = p.b_out[h];
#pragma unroll
    for (int r = 0; r < 4; r++) acc[r] += __shfl_xor(acc[r], 32, 64);
    if (lane < 32) {
#pragma unroll
        for (int r = 0; r < 4; r++) p.out[(t0 + r) * HH + h] = acc[r] + bo;
    }
}

extern "C" void kernel_launch(void* const* d_in, const int* in_sizes, int n_in,
                              void* d_out, int out_size, void* d_ws, size_t ws_size,
                              hipStream_t stream) {
    P p;
    p.emb   = (const float*)d_in[0];
    p.start = (const int*)  d_in[1];
    p.w_in  = (const float*)d_in[2];
    p.b_in  = (const float*)d_in[3];
    p.w_out = (const float*)d_in[4];
    p.b_out = (const float*)d_in[5];
    p.w_f   = (const float*)d_in[6];
    p.b_f   = (const float*)d_in[7];
    p.w_i   = (const float*)d_in[8];
    p.b_i   = (const float*)d_in[9];
    p.w_v   = (const float*)d_in[10];
    p.b_v   = (const float*)d_in[11];
    p.w_q   = (const float*)d_in[12];
    p.b_q   = (const float*)d_in[13];
    p.w_k   = (const float*)d_in[14];
    p.b_k   = (const float*)d_in[15];
    p.w_o   = (const float*)d_in[16];
    p.b_o   = (const float*)d_in[17];
    p.w_ff  = (const float*)d_in[18];
    p.b_ff  = (const float*)d_in[19];
    p.out   = (float*)d_out;

    float* ws = (float*)d_ws;
    p.e    = ws; ws += TT * HH;
    p.k0   = ws; ws += TT * HH;
    p.v0   = ws; ws += TT * HH;
    p.q0   = ws; ws += TT * HH;
    p.o0   = ws; ws += TT * HH;
    p.k1   = ws; ws += TT * HH;
    p.v1   = ws; ws += TT * HH;
    p.q1   = ws; ws += TT * HH;
    p.o1   = ws; ws += TT * HH;
    p.aux0 = ws; ws += TT * 4;
    p.aux1 = ws; ws += TT * 4;

    k1<<<dim3(NB), dim3(256), 0, stream>>>(p);
    k2<<<dim3(NB), dim3(256), 0, stream>>>(p);
    k3<<<dim3(NB), dim3(256), 0, stream>>>(p);
}